// Round 10
// baseline (218.598 us; speedup 1.0000x reference)
//
#include <hip/hip_runtime.h>
#include <hip/hip_bf16.h>
#include <math.h>

#define B 8
#define C 512
#define L 2048

using bf16x8 = __bf16 __attribute__((ext_vector_type(8)));
using f32x4  = float __attribute__((ext_vector_type(4)));

#define MFMA(a, b, c) __builtin_amdgcn_mfma_f32_16x16x32_bf16((a), (b), (c), 0, 0, 0)
// exp(v*SCALE - 12) == exp2(v*SC2 + SH2), SCALE = 1/sqrt(512)
#define SC2 0.06375872f
#define SH2 -17.312340f
// rule #18: lgkm wait must be followed by sched_barrier(0) or MFMA hoists past.
#define LGKMC(n) do { asm volatile("s_waitcnt lgkmcnt(" #n ")" ::: "memory"); \
                      __builtin_amdgcn_sched_barrier(0); } while (0)

// RNE f32->bf16 without NaN handling (all values here are finite)
__device__ __forceinline__ unsigned short f2bf(float f) {
    unsigned int u; __builtin_memcpy(&u, &f, 4);
    u += 0x7FFF + ((u >> 16) & 1);
    return (unsigned short)(u >> 16);
}
// async global->LDS, 16B/lane; LDS dest = wave-uniform base + lane*16
__device__ __forceinline__ void load_lds16(const unsigned short* g, unsigned short* l) {
    __builtin_amdgcn_global_load_lds(
        (const __attribute__((address_space(1))) unsigned int*)g,
        (__attribute__((address_space(3))) unsigned int*)l, 16, 0, 0);
}
// inline-asm ds_read_b128: invisible to the waitcnt pass; ordering via
// explicit counted lgkmcnt. Proven correct R2/R3/R9.
__device__ __forceinline__ bf16x8 dsr128(unsigned byteoff) {
    bf16x8 r;
    asm volatile("ds_read_b128 %0, %1" : "=v"(r) : "v"(byteoff));
    return r;
}

// ---------------------------------------------------------------------------
// dbuf_gemm128 (R9, proven): 128x128 tile, BK=64, 512 thr = 8 waves
// (2M x 4N of 64x32 each), double-buffered 64 KiB LDS -> 2 blocks/CU.
// Used by pv_gemm3 (K=2048), where it measured best-in-session.
// ---------------------------------------------------------------------------
template<int KDIM>
__device__ __forceinline__ void dbuf_gemm128(
    const unsigned short* __restrict__ gA, int lda,   // pre-offset: +r0*lda+swz
    const unsigned short* __restrict__ gB, int ldb,
    unsigned short* AsBase, unsigned short* BsBase,   // [2][8192] each
    f32x4 (&acc)[4][2])
{
    const int t = threadIdx.x;
    const int wave = t >> 6;
    const int ll = t & 15, quad = (t >> 4) & 3;
    const int wm = (wave & 1) * 64, wn = (wave >> 1) * 32;
    const int sw8 = ll & 7;
    const unsigned c0b = (unsigned)((quad ^ sw8) * 16);
    const unsigned c1b = (unsigned)(((4 + quad) ^ sw8) * 16);
    const unsigned ldsA = (unsigned)(unsigned long long)AsBase;
    const unsigned ldsB = (unsigned)(unsigned long long)BsBase;
    const unsigned aOff = (unsigned)((wm + ll) * 128);   // row base, bytes
    const unsigned bOff = (unsigned)((wn + ll) * 128);
    unsigned short* lA = AsBase + wave * 512;            // wave-uniform dest
    unsigned short* lB = BsBase + wave * 512;
    constexpr int NT = KDIM / 64;

    load_lds16(gA,                    lA);
    load_lds16(gA + (size_t)64 * lda, lA + 4096);
    load_lds16(gB,                    lB);
    load_lds16(gB + (size_t)64 * ldb, lB + 4096);
    __syncthreads();

    int cur = 0;
#pragma unroll 1
    for (int kt = 0; kt < NT; ++kt) {
        if (kt + 1 < NT) {                      // stage-first (uniform branch)
            const int k1 = (kt + 1) * 64;
            unsigned short* sA = lA + (cur ^ 1) * 8192;
            unsigned short* sB = lB + (cur ^ 1) * 8192;
            load_lds16(gA + k1,                    sA);
            load_lds16(gA + (size_t)64 * lda + k1, sA + 4096);
            load_lds16(gB + k1,                    sB);
            load_lds16(gB + (size_t)64 * ldb + k1, sB + 4096);
        }
        const unsigned aAdr = ldsA + (unsigned)(cur * 16384) + aOff;
        const unsigned bAdr = ldsB + (unsigned)(cur * 16384) + bOff;
        bf16x8 a0[4], b0[2], a1[4], b1[2];
        a0[0] = dsr128(aAdr + 0 * 2048 + c0b);
        a0[1] = dsr128(aAdr + 1 * 2048 + c0b);
        a0[2] = dsr128(aAdr + 2 * 2048 + c0b);
        a0[3] = dsr128(aAdr + 3 * 2048 + c0b);
        b0[0] = dsr128(bAdr + 0 * 2048 + c0b);
        b0[1] = dsr128(bAdr + 1 * 2048 + c0b);
        a1[0] = dsr128(aAdr + 0 * 2048 + c1b);
        a1[1] = dsr128(aAdr + 1 * 2048 + c1b);
        a1[2] = dsr128(aAdr + 2 * 2048 + c1b);
        a1[3] = dsr128(aAdr + 3 * 2048 + c1b);
        b1[0] = dsr128(bAdr + 0 * 2048 + c1b);
        b1[1] = dsr128(bAdr + 1 * 2048 + c1b);
        LGKMC(6);
        __builtin_amdgcn_s_setprio(1);
#pragma unroll
        for (int mi = 0; mi < 4; ++mi)
#pragma unroll
            for (int ni = 0; ni < 2; ++ni)
                acc[mi][ni] = MFMA(a0[mi], b0[ni], acc[mi][ni]);
        __builtin_amdgcn_s_setprio(0);
        LGKMC(0);
        __builtin_amdgcn_s_setprio(1);
#pragma unroll
        for (int mi = 0; mi < 4; ++mi)
#pragma unroll
            for (int ni = 0; ni < 2; ++ni)
                acc[mi][ni] = MFMA(a1[mi], b1[ni], acc[mi][ni]);
        __builtin_amdgcn_s_setprio(0);
        __syncthreads();
        cur ^= 1;
    }
}

// ---------------------------------------------------------------------------
// GEMM-NT core (legacy 128x128, 2-barrier): used by qkv_gemm (CONTROL) and
// the fallback pv path.
// ---------------------------------------------------------------------------
template<int MODE, int KDIM>
__device__ __forceinline__ void gemm_core(
    const unsigned short* __restrict__ A,
    const unsigned short* __restrict__ Bm,
    unsigned short* As, unsigned short* Bs,
    void* __restrict__ OutV, int ldo,
    float* __restrict__ ep)
{
    const int t = threadIdx.x;
    const int wave = t >> 6, lane = t & 63;
    const int ll = t & 15, quad = (t >> 4) & 3;
    const int lr = lane >> 2, chunk = lane & 3;
    const int wm = (wave & 1) * 64, wn = (wave >> 1) * 64;

    const unsigned short* gA0 = A  + (size_t)(wave * 32 + lr) * KDIM + chunk * 8;
    const unsigned short* gB0 = Bm + (size_t)(wave * 32 + lr) * KDIM + chunk * 8;
    unsigned short* lA0 = As + (wave * 32) * 32;
    unsigned short* lB0 = Bs + (wave * 32) * 32;
    const int P1 = 128 * 32;

    f32x4 acc[4][4];
#pragma unroll
    for (int i = 0; i < 4; ++i)
#pragma unroll
        for (int j = 0; j < 4; ++j) acc[i][j] = (f32x4){0.f, 0.f, 0.f, 0.f};

#pragma unroll 1
    for (int k0 = 0; k0 < KDIM; k0 += 64) {
        __syncthreads();
        load_lds16(gA0 + k0, lA0);
        load_lds16(gA0 + (size_t)16 * KDIM + k0, lA0 + 16 * 32);
        load_lds16(gA0 + k0 + 32, lA0 + P1);
        load_lds16(gA0 + (size_t)16 * KDIM + k0 + 32, lA0 + P1 + 16 * 32);
        load_lds16(gB0 + k0, lB0);
        load_lds16(gB0 + (size_t)16 * KDIM + k0, lB0 + 16 * 32);
        load_lds16(gB0 + k0 + 32, lB0 + P1);
        load_lds16(gB0 + (size_t)16 * KDIM + k0 + 32, lB0 + P1 + 16 * 32);
        __syncthreads();

#pragma unroll
        for (int p = 0; p < 2; ++p) {
            bf16x8 af[4], bf[4];
#pragma unroll
            for (int mi = 0; mi < 4; ++mi)
                af[mi] = *(const bf16x8*)&As[p * P1 + (wm + mi * 16 + ll) * 32 + quad * 8];
#pragma unroll
            for (int ni = 0; ni < 4; ++ni)
                bf[ni] = *(const bf16x8*)&Bs[p * P1 + (wn + ni * 16 + ll) * 32 + quad * 8];
#pragma unroll
            for (int mi = 0; mi < 4; ++mi)
#pragma unroll
                for (int ni = 0; ni < 4; ++ni)
                    acc[mi][ni] = MFMA(af[mi], bf[ni], acc[mi][ni]);
        }
    }

#pragma unroll
    for (int mi = 0; mi < 4; ++mi)
#pragma unroll
        for (int ni = 0; ni < 4; ++ni) {
            const int col = wn + ni * 16 + ll;
            float epc = 0.f;
            if (MODE == 0) epc = ep[col];
            if (MODE == 3) epc = 1.0f / ep[col];
#pragma unroll
            for (int r = 0; r < 4; ++r) {
                const int row = wm + mi * 16 + quad * 4 + r;
                float v = acc[mi][ni][r];
                if (MODE == 0)      v += epc;
                else if (MODE == 1) v += ep[row];
                else                v *= epc;
                if (MODE == 3)
                    ((float*)OutV)[(size_t)row * ldo + col] = v;
                else
                    ((unsigned short*)OutV)[(size_t)row * ldo + col] = f2bf(v);
            }
        }
}

// ---------------------------------------------------------------------------
// Kernel 0 (merged): x transpose/cvt + W cvt + rsum zero. Grid dim3(32,8,8).
// ---------------------------------------------------------------------------
__global__ __launch_bounds__(256) void prep(
    const float* __restrict__ x, const float* __restrict__ Wq,
    const float* __restrict__ Wk, const float* __restrict__ Wv,
    unsigned short* __restrict__ xt, unsigned short* __restrict__ o,
    float* __restrict__ rsum)
{
    __shared__ float tile[64][69];
    const int t = threadIdx.x;
    const int flat = blockIdx.x + 32 * (blockIdx.y + 8 * blockIdx.z);

    if (flat < 768) {
        if (flat < 16) {
            float4 z = make_float4(0.f, 0.f, 0.f, 0.f);
            *(float4*)(rsum + (flat * 256 + t) * 4) = z;
        }
        const int i = (flat * 256 + t) * 4;
        const int which = i >> 18;
        const int off = i & 0x3FFFF;
        const float* src = (which == 0) ? Wq : (which == 1) ? Wk : Wv;
        float4 v = *(const float4*)(src + off);
        union { unsigned short h[4]; uint2 u; } pk;
        pk.h[0] = f2bf(v.x); pk.h[1] = f2bf(v.y); pk.h[2] = f2bf(v.z); pk.h[3] = f2bf(v.w);
        *(uint2*)(o + i) = pk.u;
    }

    const int b = blockIdx.z, l0 = blockIdx.x * 64, c0 = blockIdx.y * 64;
    const int lx = t & 15, cy = t >> 4;
    const float* xb = x + (size_t)b * C * L;
#pragma unroll
    for (int p = 0; p < 4; ++p) {
        float4 v = *(const float4*)(xb + (size_t)(c0 + p * 16 + cy) * L + l0 + lx * 4);
        tile[p * 16 + cy][lx * 4 + 0] = v.x;
        tile[p * 16 + cy][lx * 4 + 1] = v.y;
        tile[p * 16 + cy][lx * 4 + 2] = v.z;
        tile[p * 16 + cy][lx * 4 + 3] = v.w;
    }
    __syncthreads();
    const int ocl = t & 15, ot = t >> 4;
    unsigned short* xtb = xt + (size_t)b * L * C;
#pragma unroll
    for (int p = 0; p < 4; ++p) {
        int ol = p * 16 + ot;
        union { unsigned short h[4]; uint2 u; } pk;
#pragma unroll
        for (int i = 0; i < 4; ++i) pk.h[i] = f2bf(tile[ocl * 4 + i][ol]);
        *(uint2*)(xtb + (size_t)(l0 + ol) * C + c0 + ocl * 4) = pk.u;
    }
}

// ---------------------------------------------------------------------------
// Kernel 1 (CONTROL, unchanged): QKV projection, legacy core. 1-D grid 1536.
// ---------------------------------------------------------------------------
__global__ __launch_bounds__(256) void qkv_gemm(
    const unsigned short* __restrict__ xt, const unsigned short* __restrict__ Wb,
    const float* __restrict__ bq, const float* __restrict__ bk,
    const float* __restrict__ bv,
    unsigned short* __restrict__ Qt, unsigned short* __restrict__ Kt,
    unsigned short* __restrict__ Vv)
{
    __shared__ unsigned short As[2 * 128 * 32], Bs[2 * 128 * 32];
    const int id = blockIdx.x;
    const int b = id & 7, r = id >> 3;
    const int which = r >> 6, tt = r & 63;
    const unsigned short* xtb = xt + (size_t)b * L * C;
    if (which < 2) {
        const int m0 = (tt & 15) * 128, n0 = (tt >> 4) * 128;
        const unsigned short* A  = xtb + (size_t)m0 * C;
        const unsigned short* Bm = Wb + (size_t)which * C * C + (size_t)n0 * C;
        unsigned short* Out = (which ? Kt : Qt) + (size_t)b * L * C
                              + (size_t)m0 * C + n0;
        gemm_core<0, C>(A, Bm, As, Bs, Out, C,
                        const_cast<float*>((which ? bk : bq) + n0));
    } else {
        const int m0 = (tt & 3) * 128, n0 = (tt >> 2) * 128;
        const unsigned short* A  = Wb + (size_t)2 * C * C + (size_t)m0 * C;
        const unsigned short* Bm = xtb + (size_t)n0 * C;
        unsigned short* Out = Vv + (size_t)b * C * L + (size_t)m0 * L + n0;
        gemm_core<1, C>(A, Bm, As, Bs, Out, L, const_cast<float*>(bv + m0));
    }
}

// ---------------------------------------------------------------------------
// Kernel 2 (NEW geometry): P = exp(Q K^T * scale - 12) + row-sum atomics.
// m201 geometry: 256x256 tile, 8 waves (2M x 4N), PER-WAVE 128x64
// (acc[8][4] = 128 VGPR), BK=64, double-buffered 128 KiB LDS, 1 block/CU,
// R9's stage-first 1-barrier dbuf structure, proven XOR swizzle.
// Rationale: per-MFMA overhead at 64x64/wave = 16 ds_read per 32 MFMA
// (512 LDS-B/MFMA) pins MfmaUtil at 22% in ALL schedules; 128x64/wave
// cuts it to 24 reads per 64 MFMA (384 B/MFMA) and halves VALU/issue
// work per MFMA. launch_bounds(512,2): VGPR cap 256 (live est. ~240).
// ---------------------------------------------------------------------------
__global__ __launch_bounds__(512, 2) void sc_exp5(
    const unsigned short* __restrict__ Qt, const unsigned short* __restrict__ Kt,
    unsigned short* __restrict__ P, float* __restrict__ rsum,
    int hoff, int qrows, int mshift)
{
    __shared__ unsigned short As[2][16384], Bs[2][16384];   // 128 KiB
    constexpr int NT = C / 64;   // 8 K-tiles

    const int id = blockIdx.x;
    const int b = id & 7, rr = id >> 3;
    const int m0 = (rr & ((1 << mshift) - 1)) * 256, n0 = (rr >> mshift) * 256;

    const int t = threadIdx.x;
    const int wave = t >> 6;
    const int ll = t & 15, quad = (t >> 4) & 3;
    const int wm = wave & 1, wn = wave >> 1;             // 2M x 4N waves
    const int sw8 = ll & 7;
    const unsigned c0b = (unsigned)((quad ^ sw8) * 16);
    const unsigned c1b = (unsigned)(((4 + quad) ^ sw8) * 16);
    const unsigned ldsA = (unsigned)(unsigned long long)&As[0][0];
    const unsigned ldsB = (unsigned)(unsigned long long)&Bs[0][0];
    const unsigned aOff = (unsigned)((wm * 128 + ll) * 128);  // bytes
    const unsigned bOff = (unsigned)((wn * 64  + ll) * 128);

    // staging: thread t covers row r0 = t>>3 (64 rows per gload), chunk t&7;
    // fetch global chunk (t&7)^(r0&7)  [inverse swizzle]
    const int r0 = t >> 3;
    const int swz = ((t & 7) ^ (r0 & 7)) * 8;
    const unsigned short* gA = Qt + (size_t)b * L * C
                               + (size_t)(hoff + m0 + r0) * C + swz;
    const unsigned short* gB = Kt + (size_t)b * L * C
                               + (size_t)(n0 + r0) * C + swz;
    unsigned short* lA = &As[0][0] + wave * 512;         // wave-uniform dest
    unsigned short* lB = &Bs[0][0] + wave * 512;

    f32x4 acc[8][4];
#pragma unroll
    for (int i = 0; i < 8; ++i)
#pragma unroll
        for (int j = 0; j < 4; ++j) acc[i][j] = (f32x4){0.f, 0.f, 0.f, 0.f};

    // prologue: stage K-tile 0 into buf 0 (A 4 gloads, B 4), drain
    load_lds16(gA,                    lA);
    load_lds16(gA + (size_t)64  * C,  lA + 4096);
    load_lds16(gA + (size_t)128 * C,  lA + 8192);
    load_lds16(gA + (size_t)192 * C,  lA + 12288);
    load_lds16(gB,                    lB);
    load_lds16(gB + (size_t)64  * C,  lB + 4096);
    load_lds16(gB + (size_t)128 * C,  lB + 8192);
    load_lds16(gB + (size_t)192 * C,  lB + 12288);
    __syncthreads();

    int cur = 0;
#pragma unroll 1
    for (int kt = 0; kt < NT; ++kt) {
        if (kt + 1 < NT) {                      // stage-first
            const int k1 = (kt + 1) * 64;
            unsigned short* sA = lA + (cur ^ 1) * 16384;
            unsigned short* sB = lB + (cur ^ 1) * 16384;
            load_lds16(gA + k1,                    sA);
            load_lds16(gA + (size_t)64  * C + k1,  sA + 4096);
            load_lds16(gA + (size_t)128 * C + k1,  sA + 8192);
            load_lds16(gA + (size_t)192 * C + k1,  sA + 12288);
            load_lds16(gB + k1,                    sB);
            load_lds16(gB + (size_t)64  * C + k1,  sB + 4096);
            load_lds16(gB + (size_t)128 * C + k1,  sB + 8192);
            load_lds16(gB + (size_t)192 * C + k1,  sB + 12288);
        }
        const unsigned aAdr = ldsA + (unsigned)(cur * 32768) + aOff;
        const unsigned bAdr = ldsB + (unsigned)(cur * 32768) + bOff;
        bf16x8 a0[8], b0[4], a1[8], b1[4];
        // issue all h0 (12) then h1 (12); counted split below
#pragma unroll
        for (int mi = 0; mi < 8; ++mi) a0[mi] = dsr128(aAdr + mi * 2048 + c0b);
#pragma unroll
        for (int ni = 0; ni < 4; ++ni) b0[ni] = dsr128(bAdr + ni * 2048 + c0b);
#pragma unroll
        for (int mi = 0; mi < 8; ++mi) a1[mi] = dsr128(aAdr + mi * 2048 + c1b);
#pragma unroll
        for (int ni = 0; ni < 4; ++ni) b1[ni] = dsr128(bAdr + ni * 2048 + c1b);
        LGKMC(12);                              // h0's 12 frags landed
        __builtin_amdgcn_s_setprio(1);
#pragma unroll
        for (int mi = 0; mi < 8; ++mi)
#pragma unroll
            for (int ni = 0; ni < 4; ++ni)
                acc[mi][ni] = MFMA(a0[mi], b0[ni], acc[mi][ni]);
        __builtin_amdgcn_s_setprio(0);
        LGKMC(0);                               // h1's 12 frags landed
        __builtin_amdgcn_s_setprio(1);
#pragma unroll
        for (int mi = 0; mi < 8; ++mi)
#pragma unroll
            for (int ni = 0; ni < 4; ++ni)
                acc[mi][ni] = MFMA(a1[mi], b1[ni], acc[mi][ni]);
        __builtin_amdgcn_s_setprio(0);
        __syncthreads();                        // drains stage(kt+1); swap
        cur ^= 1;
    }

    // epilogue: exp2, bf16 store, fused row-sum atomics
    unsigned short* Out = P + (size_t)b * qrows * L + (size_t)m0 * L + n0;
    float* ep = rsum + (size_t)b * L + hoff + m0;

    float rpart[8][4];
#pragma unroll
    for (int mi = 0; mi < 8; ++mi)
#pragma unroll
        for (int r = 0; r < 4; ++r) rpart[mi][r] = 0.f;

#pragma unroll
    for (int mi = 0; mi < 8; ++mi)
#pragma unroll
        for (int ni = 0; ni < 4; ++ni) {
            const int col = wn * 64 + ni * 16 + ll;
#pragma unroll
            for (int r = 0; r < 4; ++r) {
                const int row = wm * 128 + mi * 16 + quad * 4 + r;
                float v = exp2f(fmaf(acc[mi][ni][r], SC2, SH2));
                rpart[mi][r] += v;
                Out[(size_t)row * L + col] = f2bf(v);
            }
        }
#pragma unroll
    for (int mi = 0; mi < 8; ++mi)
#pragma unroll
        for (int r = 0; r < 4; ++r) {
            float s = rpart[mi][r];
            s += __shfl_xor(s, 1, 64);
            s += __shfl_xor(s, 2, 64);
            s += __shfl_xor(s, 4, 64);
            s += __shfl_xor(s, 8, 64);
            if (ll == 0) atomicAdd(ep + wm * 128 + mi * 16 + quad * 4 + r, s);
        }
}

// ---------------------------------------------------------------------------
// Kernel 3 (R9, proven): O = (V @ P^T) / rsum[col]. 128x128 on dbuf_gemm128,
// K = L = 2048. Grid 512: b = id&7, rr = id>>3, m = rr&3, n = rr>>2.
// ---------------------------------------------------------------------------
__global__ __launch_bounds__(512, 4) void pv_gemm3(
    const unsigned short* __restrict__ Vv, const unsigned short* __restrict__ P,
    const float* __restrict__ rsum, float* __restrict__ out)
{
    __shared__ unsigned short As[2][8192], Bs[2][8192];
    const int id = blockIdx.x;
    const int b = id & 7, rr = id >> 3;
    const int m0 = (rr & 3) * 128, n0 = (rr >> 2) * 128;

    const int t = threadIdx.x;
    const int r0 = t >> 3;
    const int swz = ((t & 7) ^ (r0 & 7)) * 8;
    const unsigned short* gA = Vv + (size_t)b * C * L
                               + (size_t)(m0 + r0) * L + swz;
    const unsigned short* gB = P + (size_t)b * L * L
                               + (size_t)(n0 + r0) * L + swz;

    f32x4 acc[4][2];
#pragma unroll
    for (int i = 0; i < 4; ++i)
#pragma unroll
        for (int j = 0; j < 2; ++j) acc[i][j] = (f32x4){0.f, 0.f, 0.f, 0.f};

    dbuf_gemm128<L>(gA, L, gB, L, &As[0][0], &Bs[0][0], acc);

    float* Out = out + (size_t)b * C * L + (size_t)m0 * L + n0;
    const float* ep = rsum + (size_t)b * L + n0;
    const int wave = t >> 6;
    const int ll = t & 15, quad = (t >> 4) & 3;
    const int wm = (wave & 1) * 64, wn = (wave >> 1) * 32;

#pragma unroll
    for (int mi = 0; mi < 4; ++mi)
#pragma unroll
        for (int ni = 0; ni < 2; ++ni) {
            const int col = wn + ni * 16 + ll;
            const float inv = 1.0f / ep[col];
#pragma unroll
            for (int r = 0; r < 4; ++r) {
                const int row = wm + mi * 16 + quad * 4 + r;
                Out[(size_t)row * L + col] = acc[mi][ni][r] * inv;
            }
        }
}

// ---------------------------------------------------------------------------
// Fallback pv (ws too small for full P): legacy 128x128 core
// ---------------------------------------------------------------------------
__global__ __launch_bounds__(256) void pv_gemm(
    const unsigned short* __restrict__ Vv, const unsigned short* __restrict__ P,
    const float* __restrict__ rsum, float* __restrict__ out,
    int hoff, int qrows)
{
    __shared__ unsigned short As[2 * 128 * 32], Bs[2 * 128 * 32];
    const int id = blockIdx.x;
    const int b = id & 7, r = id >> 3;
    const int m0 = (r & 3) * 128, n0 = (r >> 2) * 128;
    const unsigned short* A  = Vv + (size_t)b * C * L + (size_t)m0 * L;
    const unsigned short* Bm = P + (size_t)b * qrows * L + (size_t)n0 * L;
    float* Out = out + (size_t)b * C * L + (size_t)m0 * L + hoff + n0;
    float* ep = const_cast<float*>(rsum) + (size_t)b * L + hoff + n0;
    gemm_core<3, L>(A, Bm, As, Bs, Out, L, ep);
}

extern "C" void kernel_launch(void* const* d_in, const int* in_sizes, int n_in,
                              void* d_out, int out_size, void* d_ws, size_t ws_size,
                              hipStream_t stream) {
    const float* x  = (const float*)d_in[0];
    const float* Wq = (const float*)d_in[1];
    const float* bq = (const float*)d_in[2];
    const float* Wk = (const float*)d_in[3];
    const float* bk = (const float*)d_in[4];
    const float* Wv = (const float*)d_in[5];
    const float* bv = (const float*)d_in[6];
    float* out = (float*)d_out;

    const size_t BCL = (size_t)B * C * L;                // 8.39M elems
    const bool fullP = ws_size >= 119078912ull;          // full-P footprint

    unsigned short* Qt = (unsigned short*)d_ws;          // [B][L][C] bf16
    unsigned short* Kt = Qt + BCL;
    unsigned short* Vv = Kt + BCL;                       // [B][C][L]
    unsigned short *Wb, *xt, *P;
    float* rsum;
    if (fullP) {
        Wb   = Vv + BCL;                                 // 1.57 MB, live during qkv
        rsum = (float*)(Wb + (size_t)3 * C * C);         // [B][L] f32
        xt   = (unsigned short*)(rsum + (size_t)B * L);  // dead after qkv
        P    = xt;                                       // [B][L][L] bf16, aliases xt
    } else {                                             // 85.6 MB fallback
        xt   = Vv + BCL;
        P    = xt;                                       // [B][1024][L], aliases xt
        Wb   = P + (size_t)B * 1024 * L;
        rsum = (float*)(Wb + (size_t)3 * C * C);
    }

    prep<<<dim3(L / 64, C / 64, B), 256, 0, stream>>>(x, Wq, Wk, Wv, xt, Wb, rsum);
    qkv_gemm<<<dim3(1536), 256, 0, stream>>>(xt, Wb, bq, bk, bv, Qt, Kt, Vv);

    if (fullP) {
        // sc: 8 m-tiles x 8 n-tiles x 8 b = 512 blocks (mshift=3, 256x256)
        sc_exp5<<<dim3(512), 512, 0, stream>>>(Qt, Kt, P, rsum, 0, L, 3);
        // pv: 4 m x 16 n x 8 b = 512 blocks
        pv_gemm3<<<dim3(512), 512, 0, stream>>>(Vv, P, rsum, out);
    } else {
        for (int h = 0; h < 2; ++h) {
            // sc: 4 m x 8 n x 8 b = 256 blocks (mshift=2)
            sc_exp5<<<dim3(256), 512, 0, stream>>>(Qt, Kt, P, rsum, h * 1024, 1024, 2);
            pv_gemm<<<dim3(256), 256, 0, stream>>>(Vv, P, rsum, out, h * 1024, 1024);
        }
    }
}